// Round 14
// baseline (635.080 us; speedup 1.0000x reference)
//
#include <hip/hip_runtime.h>
#include <cstdint>
#include <cstddef>

#define EPSF 1e-5f

// Dims (fixed by the problem)
#define BB 8
#define CC 128
#define HH 64
#define TT 512
#define HW (HH*TT)          // 32768
#define NPIX (BB*HH*TT)     // 262144

__device__ __forceinline__ float rcpf(float x) { return __builtin_amdgcn_rcpf(x); }
__device__ __forceinline__ float sigf(float x) { return rcpf(1.f + __expf(-x)); }

// Branch-free erf (Abramowitz-Stegun 7.1.26, |err| <= 1.5e-7), rcp-based
__device__ __forceinline__ float erf_fast(float x) {
    float ax = fabsf(x);
    float t = rcpf(1.f + 0.3275911f * ax);
    float y = t * (0.254829592f + t * (-0.284496736f + t * (1.421413741f
               + t * (-1.453152027f + t * 1.061405429f))));
    float r = 1.f - y * __expf(-ax * ax);
    return copysignf(r, x);
}
__device__ __forceinline__ float geluf(float z) {
    return 0.5f * z * (1.f + erf_fast(z * 0.70710678118654752f));
}

// bf16 <-> f32 (RNE)
__device__ __forceinline__ unsigned short f2u(float f) {
    unsigned int u = __builtin_bit_cast(unsigned int, f);
    u += 0x7fffu + ((u >> 16) & 1u);
    return (unsigned short)(u >> 16);
}
__device__ __forceinline__ float u2f(unsigned short s) {
    return __builtin_bit_cast(float, (unsigned int)s << 16);
}
__device__ __forceinline__ float u2f_lo(unsigned x) {
    return __builtin_bit_cast(float, x << 16);
}
__device__ __forceinline__ float u2f_hi(unsigned x) {
    return __builtin_bit_cast(float, x & 0xffff0000u);
}

typedef __attribute__((ext_vector_type(8))) short bf16x8;
typedef __attribute__((ext_vector_type(4))) float f32x4;

// X-tile LDS offset: +8 shorts (16B) pad every 8 rows breaks the structural
// 8-way bank conflict of 16B-aligned row strides; keeps 16B alignment.
#define XO(t, CSTR) ((t) * (CSTR) + ((t) >> 3) * 8)

// ---------------------------------------------------------------------------
// Weight prep: 8 pw weight matrices f32 -> bf16 in MFMA-FRAGMENT-SHUFFLED
// order: per slot [og(4)][f(2)][ks(KS)][lane(64)][e(8)].
// slot0: w_in (CIN=64), 1:b1_pwa 2:b1_pwb 3:b1_d1p 4:b2_pwa 5:b2_pwb
// 6:b2_d1p 7:w_out (CIN=128).
// ---------------------------------------------------------------------------
__global__ __launch_bounds__(256) void prep_weights(const float* __restrict__ s0,
                                                    const float* __restrict__ s1,
                                                    const float* __restrict__ s2,
                                                    const float* __restrict__ s3,
                                                    const float* __restrict__ s4,
                                                    const float* __restrict__ s5,
                                                    const float* __restrict__ s6,
                                                    const float* __restrict__ s7,
                                                    unsigned short* __restrict__ wbf)
{
    int gid = blockIdx.x * 256 + threadIdx.x;     // 0..131071
    int slot = gid >> 14, idx = gid & 16383;
    const float* srcs[8] = {s0, s1, s2, s3, s4, s5, s6, s7};
    const int CIN = (slot == 0) ? 64 : 128;
    const int KS = CIN / 32;
    float v = 0.f;
    if (slot != 0 || idx < 8192) {
        int e = idx & 7, lane = (idx >> 3) & 63;
        int rest = idx >> 9;
        int ks = rest % KS, f = (rest / KS) & 1, og = rest / (2 * KS);
        int row = og * 32 + f * 16 + (lane & 15);
        int col = ks * 32 + (lane >> 4) * 8 + e;
        v = srcs[slot][row * CIN + col];
    }
    wbf[gid] = f2u(v);
}

// ---------------------------------------------------------------------------
// Pointwise conv via bf16 MFMA. W fragments coalesced into registers;
// X tile transposed in LDS (XO padding). CPOOL: per-block channel-pool
// partials -> cpart[(b*128+row)*1024 + slot] (sums) / +512 (maxes).
// SPOOL: per-pixel mean/max -> sspat. Grid 4096, 256 threads.
// ---------------------------------------------------------------------------
template<int CIN, int ACT, bool FLIP, bool BN, bool INF32, bool OUTF32, bool CPOOL, bool SPOOL>
__global__ __launch_bounds__(256) void pw_mfma(const void* __restrict__ inv,
                                               const unsigned short* __restrict__ Wb,
                                               const float* __restrict__ bnp,
                                               void* __restrict__ outv,
                                               float* __restrict__ cpart,
                                               float* __restrict__ sspat)
{
    constexpr int CSTR = CIN + 8;
    constexpr int KS = CIN / 32;
    constexpr int CP = CIN / 32;          // c-rows per staging thread
    __shared__ unsigned short Xl[64 * CSTR + 64];
    __shared__ float bns[128], bnh[128];
    __shared__ float spsum[4][64], spmax[4][64];

    const int tid = threadIdx.x;
    const int bh = blockIdx.x >> 3, tt = blockIdx.x & 7;
    const int b = bh >> 6, h = bh & 63;
    const int t0 = tt << 6;

    const int lane = tid & 63, wv = tid >> 6;
    const int lanel = lane & 15, laneh = lane >> 4;
    const int ob = wv * 32;

    // ---- W fragments -> registers (coalesced: lane*8 contiguous) ----
    bf16x8 afr[2][KS];
#pragma unroll
    for (int f = 0; f < 2; ++f)
#pragma unroll
        for (int ks = 0; ks < KS; ++ks)
            afr[f][ks] = *(const bf16x8*)&Wb[(size_t)wv * (2 * KS * 512)
                                             + (f * KS + ks) * 512 + lane * 8];

    if (BN && tid < 128) {
        float g = bnp[tid], be = bnp[CC + tid], m = bnp[2 * CC + tid], v = bnp[3 * CC + tid];
        float s = g * rsqrtf(v + EPSF);
        bns[tid] = s; bnh[tid] = be - m * s;
    }

    // ---- stage X transposed: Xl[t][c] ----
    {
        const int s = tid & 7, g = tid >> 3;
        const int tl0 = s * 8;
        const int c0 = g * CP;
        unsigned short vals[CP][8];
#pragma unroll
        for (int i = 0; i < CP; ++i) {
            const size_t rowbase = ((size_t)(b * CIN + c0 + i) * HH + h) * TT;
            const int tb = FLIP ? (504 - t0 - tl0) : (t0 + tl0);
            if (INF32) {
                const float* pf32 = (const float*)inv;
                float4 u0 = *(const float4*)&pf32[rowbase + tb];
                float4 u1 = *(const float4*)&pf32[rowbase + tb + 4];
                float tmp[8] = {u0.x, u0.y, u0.z, u0.w, u1.x, u1.y, u1.z, u1.w};
#pragma unroll
                for (int j = 0; j < 8; ++j) vals[i][j] = f2u(tmp[FLIP ? 7 - j : j]);
            } else {
                const unsigned short* pb = (const unsigned short*)inv;
                unsigned short tmp[8];
                *(uint4*)tmp = *(const uint4*)&pb[rowbase + tb];
#pragma unroll
                for (int j = 0; j < 8; ++j) vals[i][j] = tmp[FLIP ? 7 - j : j];
            }
        }
#pragma unroll
        for (int j = 0; j < 8; ++j) {
            unsigned short* dst = &Xl[XO(tl0 + j, CSTR) + c0];
            if (CP == 4) {
                uint2 pk;
                pk.x = (unsigned)vals[0][j] | ((unsigned)vals[1][j] << 16);
                pk.y = (unsigned)vals[2][j] | ((unsigned)vals[3][j] << 16);
                *(uint2*)dst = pk;
            } else {
                *(unsigned int*)dst = (unsigned)vals[0][j] | ((unsigned)vals[1][j] << 16);
            }
        }
    }
    __syncthreads();

    // ---- MFMA: wave tile 32 o x 64 t ----
    f32x4 acc[2][4];
#pragma unroll
    for (int f = 0; f < 2; ++f)
#pragma unroll
        for (int tf = 0; tf < 4; ++tf) acc[f][tf] = (f32x4){0.f, 0.f, 0.f, 0.f};

#pragma unroll
    for (int ks = 0; ks < KS; ++ks) {
        const int kb = ks * 32 + laneh * 8;
#pragma unroll
        for (int tf = 0; tf < 4; ++tf) {
            bf16x8 bb = *(const bf16x8*)&Xl[XO(tf * 16 + lanel, CSTR) + kb];
            acc[0][tf] = __builtin_amdgcn_mfma_f32_16x16x32_bf16(afr[0][ks], bb, acc[0][tf], 0, 0, 0);
            acc[1][tf] = __builtin_amdgcn_mfma_f32_16x16x32_bf16(afr[1][ks], bb, acc[1][tf], 0, 0, 0);
        }
    }

    // ---- epilogue: BN + act + store (+ fused pools) ----
    const size_t obase = ((size_t)(b * CC) * HH + h) * TT;
    const int slot = h * 8 + tt;                  // 0..511
    float cs[4], cm[4];
    if (SPOOL) {
#pragma unroll
        for (int tf = 0; tf < 4; ++tf) { cs[tf] = 0.f; cm[tf] = -3.4e38f; }
    }
#pragma unroll
    for (int f = 0; f < 2; ++f) {
#pragma unroll
        for (int r = 0; r < 4; ++r) {
            const int row = ob + f * 16 + laneh * 4 + r;
            const float s = BN ? bns[row] : 1.f;
            const float sh = BN ? bnh[row] : 0.f;
            float rs = 0.f, rm = -3.4e38f;
#pragma unroll
            for (int tf = 0; tf < 4; ++tf) {
                float v = acc[f][tf][r] * s + sh;
                if (ACT == 1) v = fmaxf(v, 0.f);
                if (ACT == 2) v = sigf(v);
                size_t oidx = obase + (size_t)row * HW + t0 + tf * 16 + lanel;
                if (OUTF32) ((float*)outv)[oidx] = v;
                else ((unsigned short*)outv)[oidx] = f2u(v);
                if (CPOOL) { rs += v; rm = fmaxf(rm, v); }
                if (SPOOL) { cs[tf] += v; cm[tf] = fmaxf(cm[tf], v); }
            }
            if (CPOOL) {
                rs += __shfl_xor(rs, 1); rm = fmaxf(rm, __shfl_xor(rm, 1));
                rs += __shfl_xor(rs, 2); rm = fmaxf(rm, __shfl_xor(rm, 2));
                rs += __shfl_xor(rs, 4); rm = fmaxf(rm, __shfl_xor(rm, 4));
                rs += __shfl_xor(rs, 8); rm = fmaxf(rm, __shfl_xor(rm, 8));
                if (lanel == 0) {
                    cpart[((size_t)(b * CC + row)) * 1024 + slot] = rs;
                    cpart[((size_t)(b * CC + row)) * 1024 + 512 + slot] = rm;
                }
            }
        }
    }
    if (SPOOL) {
#pragma unroll
        for (int tf = 0; tf < 4; ++tf) {
            cs[tf] += __shfl_xor(cs[tf], 16); cm[tf] = fmaxf(cm[tf], __shfl_xor(cm[tf], 16));
            cs[tf] += __shfl_xor(cs[tf], 32); cm[tf] = fmaxf(cm[tf], __shfl_xor(cm[tf], 32));
        }
        if (laneh == 0) {
#pragma unroll
            for (int tf = 0; tf < 4; ++tf) {
                spsum[wv][tf * 16 + lanel] = cs[tf];
                spmax[wv][tf * 16 + lanel] = cm[tf];
            }
        }
        __syncthreads();
        if (tid < 64) {
            float su = spsum[0][tid] + spsum[1][tid] + spsum[2][tid] + spsum[3][tid];
            float mx = fmaxf(fmaxf(spmax[0][tid], spmax[1][tid]),
                             fmaxf(spmax[2][tid], spmax[3][tid]));
            const int sp = h * TT + t0 + tid;
            sspat[((size_t)b * 2) * HW + sp] = su * (1.f / 128.f);
            sspat[((size_t)b * 2 + 1) * HW + sp] = mx;
        }
    }
}

// ---------------------------------------------------------------------------
// chan_reduce: one block per (b,c); contiguous partials, coalesced + LDS
// tree. Grid 1024 x 256.
// ---------------------------------------------------------------------------
__global__ __launch_bounds__(256) void chan_reduce(const float* __restrict__ cpart,
                                                   float* __restrict__ pavg,
                                                   float* __restrict__ pmax)
{
    __shared__ float ss[256], sm[256];
    const int bc = blockIdx.x, tid = threadIdx.x;
    const float* p = cpart + (size_t)bc * 1024;
    float s = p[tid] + p[tid + 256];
    float m = fmaxf(p[512 + tid], p[768 + tid]);
    ss[tid] = s; sm[tid] = m;
    __syncthreads();
    for (int w = 128; w > 0; w >>= 1) {
        if (tid < w) { ss[tid] += ss[tid + w]; sm[tid] = fmaxf(sm[tid], sm[tid + w]); }
        __syncthreads();
    }
    if (tid == 0) { pavg[bc] = ss[0] * (1.f / (float)HW); pmax[bc] = sm[0]; }
}

// ---------------------------------------------------------------------------
// Channel-attention MLP on precomputed pools. Grid 8 x 256.
// ---------------------------------------------------------------------------
__global__ __launch_bounds__(256) void chan_mlp(const float* __restrict__ pavg,
                                                const float* __restrict__ pmax,
                                                const float* __restrict__ w1,
                                                const float* __restrict__ w2,
                                                float* __restrict__ a)
{
    __shared__ float ua[128], um[128], hid[16];
    const int b = blockIdx.x, tid = threadIdx.x;
    if (tid < 128) { ua[tid] = pavg[b * 128 + tid]; um[tid] = pmax[b * 128 + tid]; }
    __syncthreads();
    if (tid < 16) {
        int mm = tid >> 1, path = tid & 1;
        const float* u = path ? um : ua;
        float acc = 0.f;
#pragma unroll
        for (int cc = 0; cc < 128; ++cc) acc += u[cc] * w1[mm * 128 + cc];
        hid[tid] = fmaxf(acc, 0.f);
    }
    __syncthreads();
    if (tid < 128) {
        float acc = 0.f;
#pragma unroll
        for (int mm = 0; mm < 8; ++mm) acc += (hid[2 * mm] + hid[2 * mm + 1]) * w2[tid * 8 + mm];
        a[b * 128 + tid] = sigf(acc);
    }
}

// ---------------------------------------------------------------------------
// FUSED: staging computes cb = b1^2*achan then dw1x3 -> X tile; pw(d1p)+BN+
// sigmoid via MFMA; SSM+GELU; channel-LN; * sigmoid(b2^2*aspat).
// b2 is bounced through the retired X LDS tile (coalesced reads).
// Grid 4096, 256 threads.
// ---------------------------------------------------------------------------
__global__ __launch_bounds__(256) void pw_ssm(const unsigned short* __restrict__ b1t,
                                              const unsigned short* __restrict__ Wb,
                                              const float* __restrict__ bnp,
                                              const unsigned short* __restrict__ b2t,
                                              const float* __restrict__ aspat,
                                              const float* __restrict__ sc,
                                              const float* __restrict__ Dv,
                                              const float* __restrict__ ln,
                                              const float* __restrict__ ach,
                                              const float* __restrict__ d1w,
                                              unsigned short* __restrict__ outp)
{
    constexpr int CIN = 128;
    constexpr int CSTR = CIN + 8;
    __shared__ unsigned short Xl[64 * CSTR + 64];   // reused as b2 tile later
    __shared__ float bns[128], bnh[128];
    __shared__ float sDv[128], slnw[128], slnb[128];
    __shared__ float psum[4][64], psq[4][64];
    __shared__ float smu[64], srstd[64], sas[64];

    const int tid = threadIdx.x;
    const int bh = blockIdx.x >> 3, tt = blockIdx.x & 7;
    const int b = bh >> 6, h = bh & 63;
    const int t0 = tt << 6;

    const int lane = tid & 63, wv = tid >> 6;
    const int lanel = lane & 15, laneh = lane >> 4;
    const int ob = wv * 32;
    const size_t obase = ((size_t)(b * CC) * HH + h) * TT;

    bf16x8 afr[2][4];
#pragma unroll
    for (int f = 0; f < 2; ++f)
#pragma unroll
        for (int ks = 0; ks < 4; ++ks)
            afr[f][ks] = *(const bf16x8*)&Wb[(size_t)wv * 4096 + (f * 4 + ks) * 512 + lane * 8];

    if (tid < 128) {
        float g = bnp[tid], be = bnp[CC + tid], m = bnp[2 * CC + tid], v = bnp[3 * CC + tid];
        float s = g * rsqrtf(v + EPSF);
        bns[tid] = s; bnh[tid] = be - m * s;
        sDv[tid] = Dv[tid]; slnw[tid] = ln[tid]; slnb[tid] = ln[CC + tid];
    }
    if (tid < 64) sas[tid] = aspat[((size_t)b * HH + h) * TT + t0 + tid];

    {
        const int s = tid & 7, g = tid >> 3;
        const int tl0 = s * 8;
        const int c0 = g * 4;
        const int tg = t0 + tl0;
        unsigned short vals[4][8];
#pragma unroll
        for (int i = 0; i < 4; ++i) {
            const int c = c0 + i;
            const unsigned short* p = b1t + ((size_t)(b * CC + c) * HH + h) * TT;
            const float av = ach[b * CC + c];
            const float w0 = d1w[c * 3 + 0], w1 = d1w[c * 3 + 1], w2 = d1w[c * 3 + 2];
            unsigned short raw2[8];
            *(uint4*)raw2 = *(const uint4*)&p[tg];
            float cb[10];
            cb[0] = 0.f;
            if (tg > 0) { float l = u2f(p[tg - 1]); cb[0] = l * l * av; }
            cb[9] = 0.f;
            if (tg + 8 < TT) { float rr = u2f(p[tg + 8]); cb[9] = rr * rr * av; }
#pragma unroll
            for (int j = 0; j < 8; ++j) { float x = u2f(raw2[j]); cb[j + 1] = x * x * av; }
#pragma unroll
            for (int j = 0; j < 8; ++j)
                vals[i][j] = f2u(cb[j] * w0 + cb[j + 1] * w1 + cb[j + 2] * w2);
        }
#pragma unroll
        for (int j = 0; j < 8; ++j) {
            uint2 pk;
            pk.x = (unsigned)vals[0][j] | ((unsigned)vals[1][j] << 16);
            pk.y = (unsigned)vals[2][j] | ((unsigned)vals[3][j] << 16);
            *(uint2*)&Xl[XO(tl0 + j, CSTR) + c0] = pk;
        }
    }
    __syncthreads();

    f32x4 acc[2][4];
#pragma unroll
    for (int f = 0; f < 2; ++f)
#pragma unroll
        for (int tf = 0; tf < 4; ++tf) acc[f][tf] = (f32x4){0.f, 0.f, 0.f, 0.f};

#pragma unroll
    for (int ks = 0; ks < 4; ++ks) {
        const int kb = ks * 32 + laneh * 8;
#pragma unroll
        for (int tf = 0; tf < 4; ++tf) {
            bf16x8 bb = *(const bf16x8*)&Xl[XO(tf * 16 + lanel, CSTR) + kb];
            acc[0][tf] = __builtin_amdgcn_mfma_f32_16x16x32_bf16(afr[0][ks], bb, acc[0][tf], 0, 0, 0);
            acc[1][tf] = __builtin_amdgcn_mfma_f32_16x16x32_bf16(afr[1][ks], bb, acc[1][tf], 0, 0, 0);
        }
    }

    float ps[4] = {0.f, 0.f, 0.f, 0.f}, pq[4] = {0.f, 0.f, 0.f, 0.f};
#pragma unroll
    for (int f = 0; f < 2; ++f) {
#pragma unroll
        for (int r = 0; r < 4; ++r) {
            const int row = ob + f * 16 + laneh * 4 + r;
            const float s = bns[row], sh = bnh[row], dv = sDv[row];
#pragma unroll
            for (int tf = 0; tf < 4; ++tf) {
                const int col = tf * 16 + lanel;
                float x = sigf(acc[f][tf][r] * s + sh);
                float z = sc[row * TT + t0 + col] + x * dv;
                float o = x + geluf(z);
                acc[f][tf][r] = o;
                ps[tf] += o; pq[tf] += o * o;
            }
        }
    }
#pragma unroll
    for (int tf = 0; tf < 4; ++tf) {
        ps[tf] += __shfl_xor(ps[tf], 16);
        ps[tf] += __shfl_xor(ps[tf], 32);
        pq[tf] += __shfl_xor(pq[tf], 16);
        pq[tf] += __shfl_xor(pq[tf], 32);
    }
    if (laneh == 0) {
#pragma unroll
        for (int tf = 0; tf < 4; ++tf) {
            psum[wv][tf * 16 + lanel] = ps[tf];
            psq[wv][tf * 16 + lanel] = pq[tf];
        }
    }
    __syncthreads();   // also: all Xl reads (MFMA) complete -> safe to reuse

    // ---- stage b2 tile into retired Xl: [128 rows][68 stride] bf16 ----
    {
        const int s = tid & 7, g = tid >> 3;     // col0 = s*8, rows g*4+i
#pragma unroll
        for (int i = 0; i < 4; ++i) {
            uint4 v = *(const uint4*)&b2t[obase + (size_t)(g * 4 + i) * HW + t0 + s * 8];
            *(uint4*)&Xl[(g * 4 + i) * 68 + s * 8] = v;
        }
    }
    if (tid < 64) {
        float su = psum[0][tid] + psum[1][tid] + psum[2][tid] + psum[3][tid];
        float qu = psq[0][tid] + psq[1][tid] + psq[2][tid] + psq[3][tid];
        float mu = su * (1.f / 128.f);
        float var = qu * (1.f / 128.f) - mu * mu;
        smu[tid] = mu; srstd[tid] = rsqrtf(var + EPSF);
    }
    __syncthreads();

    // ---- LN + spatial-branch multiply + store bf16 ----
#pragma unroll
    for (int f = 0; f < 2; ++f) {
#pragma unroll
        for (int r = 0; r < 4; ++r) {
            const int row = ob + f * 16 + laneh * 4 + r;
            const float lw = slnw[row], lb = slnb[row];
#pragma unroll
            for (int tf = 0; tf < 4; ++tf) {
                const int col = tf * 16 + lanel;
                float val = (acc[f][tf][r] - smu[col]) * srstd[col] * lw + lb;
                float bv = u2f(Xl[row * 68 + col]);
                float sb = sigf(bv * bv * sas[col]);
                outp[obase + (size_t)row * HW + t0 + col] = f2u(val * sb);
            }
        }
    }
}

// ---------------------------------------------------------------------------
// Depthwise 5x5 'same' conv (bf16 in/out, f32 compute), dual weight sets.
// ROUND-13: 2-t-per-thread blocking. Tile 32h x 128t (grid 8192); thread
// owns 8 h x 2 adjacent t (t=2q,2q+1). Key: output t=2q tap dj and output
// t=2q+1 tap dj-1 read the SAME column cb+dj (cb=6+2q), so a 6-iteration
// dj loop with rolling weight registers shares every val[12] column load
// between both outputs: 132 LDS reads / 32 outputs vs 110 / 16 before.
// Col map: LDS col k <-> global t0-8+k; output t needs col 6+t+dj.
// ---------------------------------------------------------------------------
template<bool FLIP>
__global__ __launch_bounds__(256) void dw5x5_dual(const unsigned short* __restrict__ in,
                                                  const float* __restrict__ wa,
                                                  const float* __restrict__ wb,
                                                  unsigned short* __restrict__ oa,
                                                  unsigned short* __restrict__ ob)
{
    __shared__ float tile[36][148];
    __shared__ float wla[25], wlb[25];
    const int tid = threadIdx.x;
    const int bc = blockIdx.x >> 3;
    const int tl3 = blockIdx.x & 7;
    const int ht = tl3 >> 2, tt = tl3 & 3;
    const int h0 = ht << 5, t0 = tt << 7;
    const int c = bc & (CC - 1);
    const unsigned short* base = in + (size_t)bc * HW;

    if (tid < 25) { wla[tid] = wa[c * 25 + tid]; wlb[tid] = wb[c * 25 + tid]; }
    // ---- vectorized staging: 36 rows x 18 segments of 8 shorts ----
    for (int task = tid; task < 648; task += 256) {
        const int r = task / 18, sg = task - r * 18;
        const int grow = h0 - 2 + r;
        const int gcol = t0 - 8 + sg * 8;
        float v[8];
        if (grow >= 0 && grow < HH && gcol >= 0 && gcol <= TT - 8) {
            const int gc = FLIP ? (TT - 8 - gcol) : gcol;
            uint4 u = *(const uint4*)&base[grow * TT + gc];
            if (FLIP) {
                uint4 rv;
                rv.x = (u.w >> 16) | (u.w << 16);
                rv.y = (u.z >> 16) | (u.z << 16);
                rv.z = (u.y >> 16) | (u.y << 16);
                rv.w = (u.x >> 16) | (u.x << 16);
                u = rv;
            }
            v[0] = u2f_lo(u.x); v[1] = u2f_hi(u.x);
            v[2] = u2f_lo(u.y); v[3] = u2f_hi(u.y);
            v[4] = u2f_lo(u.z); v[5] = u2f_hi(u.z);
            v[6] = u2f_lo(u.w); v[7] = u2f_hi(u.w);
        } else {
#pragma unroll
            for (int j = 0; j < 8; ++j) v[j] = 0.f;
        }
        float* dst = &tile[r][sg * 8];
        *(float4*)dst = (float4){v[0], v[1], v[2], v[3]};
        *(float4*)(dst + 4) = (float4){v[4], v[5], v[6], v[7]};
    }
    __syncthreads();

    const int q = tid & 63;                 // t-pair index: t = 2q, 2q+1
    const int hg = tid >> 6;                // 4 h-groups of 8 rows
    const int r0 = hg * 8;
    const int cb = 6 + 2 * q;

    float sa0[8], sa1[8], sb0[8], sb1[8];
#pragma unroll
    for (int o = 0; o < 8; ++o) { sa0[o] = 0.f; sa1[o] = 0.f; sb0[o] = 0.f; sb1[o] = 0.f; }

    float wpa[5], wpb[5];                   // rolling: w[di][dj-1]
#pragma unroll
    for (int dj = 0; dj < 6; ++dj) {
        float val[12];
#pragma unroll
        for (int k = 0; k < 12; ++k) val[k] = tile[r0 + k][cb + dj];
        float wca[5], wcb2[5];
        if (dj < 5) {
#pragma unroll
            for (int di = 0; di < 5; ++di) {
                wca[di] = wla[di * 5 + dj];
                wcb2[di] = wlb[di * 5 + dj];
            }
        }
#pragma unroll
        for (int di = 0; di < 5; ++di) {
#pragma unroll
            for (int o = 0; o < 8; ++o) {
                const float x = val[o + di];
                if (dj < 5) { sa0[o] += x * wca[di];  sb0[o] += x * wcb2[di]; }
                if (dj > 0) { sa1[o] += x * wpa[di];  sb1[o] += x * wpb[di]; }
            }
        }
        if (dj < 5) {
#pragma unroll
            for (int di = 0; di < 5; ++di) { wpa[di] = wca[di]; wpb[di] = wcb2[di]; }
        }
    }

    const size_t obase = (size_t)bc * HW + (size_t)(h0 + r0) * TT + t0 + 2 * q;
#pragma unroll
    for (int o = 0; o < 8; ++o) {
        *(unsigned*)&oa[obase + (size_t)o * TT] =
            (unsigned)f2u(sa0[o]) | ((unsigned)f2u(sa1[o]) << 16);
        *(unsigned*)&ob[obase + (size_t)o * TT] =
            (unsigned)f2u(sb0[o]) | ((unsigned)f2u(sb1[o]) << 16);
    }
}

// ---------------------------------------------------------------------------
// 7x7 conv on 2-ch pooled map + sigmoid (f32). Grid 1024x256.
// ---------------------------------------------------------------------------
__global__ __launch_bounds__(256) void spat_conv(const float* __restrict__ s,
                                                 const float* __restrict__ w,
                                                 float* __restrict__ a)
{
    __shared__ float wl[98];
    const int tid = threadIdx.x;
    if (tid < 98) wl[tid] = w[tid];
    __syncthreads();
    const int pix = blockIdx.x * 256 + tid;
    const int t = pix & 511, h = (pix >> 9) & 63, b = pix >> 15;
    float acc = 0.f;
#pragma unroll
    for (int ch = 0; ch < 2; ++ch) {
        const float* sp = s + ((size_t)b * 2 + ch) * HW;
#pragma unroll
        for (int di = 0; di < 7; ++di) {
            int hh = h + di - 3;
            if (hh < 0 || hh >= HH) continue;
#pragma unroll
            for (int dj = 0; dj < 7; ++dj) {
                int t2 = t + dj - 3;
                if (t2 < 0 || t2 >= TT) continue;
                acc += sp[hh * TT + t2] * wl[ch * 49 + di * 7 + dj];
            }
        }
    }
    a[pix] = sigf(acc);
}

// ---------------------------------------------------------------------------
// mat_powers: per SSM, compute M^(2^k) and F_(2^k) for k=0..9. Grid 2 x 256.
// ---------------------------------------------------------------------------
__global__ __launch_bounds__(256) void mat_powers(const float* __restrict__ A1,
                                                  const float* __restrict__ A2,
                                                  float* __restrict__ Mg,
                                                  float* __restrict__ Fg)
{
    const float* A = blockIdx.x ? A2 : A1;
    float* Mo = Mg + (size_t)blockIdx.x * 10240;
    float* Fo = Fg + (size_t)blockIdx.x * 10240;
    __shared__ float Mc[1024], Fc[1024], Mn[1024], Fn[1024];
    const int tid = threadIdx.x;

    for (int idx = tid; idx < 1024; idx += 256) {
        int k = idx >> 5, j = idx & 31;
        Mc[idx] = A[j * 32 + k];
        Fc[idx] = (k == j) ? 1.f : 0.f;
    }
    __syncthreads();
    for (int k = 0; k < 10; ++k) {
        for (int idx = tid; idx < 1024; idx += 256) {
            Mo[k * 1024 + idx] = Mc[idx];
            Fo[k * 1024 + idx] = Fc[idx];
        }
        if (k == 9) break;
        for (int idx = tid; idx < 1024; idx += 256) {
            int r = idx >> 5, cc = idx & 31;
            float am = 0.f, af = 0.f;
#pragma unroll
            for (int m = 0; m < 32; ++m) {
                am += Mc[r * 32 + m] * Mc[m * 32 + cc];
                af += Mc[r * 32 + m] * Fc[m * 32 + cc];
            }
            Mn[idx] = am;
            Fn[idx] = Fc[idx] + af;
        }
        __syncthreads();
        for (int idx = tid; idx < 1024; idx += 256) { Mc[idx] = Mn[idx]; Fc[idx] = Fn[idx]; }
        __syncthreads();
    }
}

// ---------------------------------------------------------------------------
// scan_apply: S[t] = B * F_{t+1} via bit-decomposition. Grid 16 x 64.
// ---------------------------------------------------------------------------
__global__ __launch_bounds__(64) void scan_apply(const float* __restrict__ B1,
                                                 const float* __restrict__ B2,
                                                 const float* __restrict__ Mg,
                                                 const float* __restrict__ Fg,
                                                 float* __restrict__ Sws)
{
    __shared__ float Ml[5][1024], Fl[5][1024];   // 40KB
    const int ssm = blockIdx.x >> 3;
    const int tb = blockIdx.x & 7;
    const float* Bv = ssm ? B2 : B1;
    const float* Mi = Mg + (size_t)ssm * 10240;
    const float* Fi = Fg + (size_t)ssm * 10240;
    float* Sg = Sws + (size_t)ssm * (TT * 32);
    const int tid = threadIdx.x;
    const int t = tb * 64 + tid;
    const int n = t + 1;

    float z[32], v[32];
#pragma unroll
    for (int j = 0; j < 32; ++j) { z[j] = 0.f; v[j] = Bv[j]; }

    for (int ph = 0; ph < 2; ++ph) {
        __syncthreads();
        for (int idx = tid; idx < 5120; idx += 64) {
            (&Ml[0][0])[idx] = Mi[ph * 5120 + idx];
            (&Fl[0][0])[idx] = Fi[ph * 5120 + idx];
        }
        __syncthreads();
        for (int kk = 0; kk < 5; ++kk) {
            const int k = ph * 5 + kk;
            if (n & (1 << k)) {
                float zn[32], vn[32];
#pragma unroll
                for (int j = 0; j < 32; ++j) { zn[j] = z[j]; vn[j] = 0.f; }
#pragma unroll
                for (int m = 0; m < 32; ++m) {
                    const float vm = v[m];
                    const float* fr = &Fl[kk][m * 32];
                    const float* mr = &Ml[kk][m * 32];
#pragma unroll
                    for (int j = 0; j < 32; ++j) {
                        zn[j] += vm * fr[j];
                        vn[j] += vm * mr[j];
                    }
                }
#pragma unroll
                for (int j = 0; j < 32; ++j) { z[j] = zn[j]; v[j] = vn[j]; }
            }
        }
    }
#pragma unroll
    for (int j = 0; j < 32; ++j) Sg[t * 32 + j] = z[j];
}

// ---------------------------------------------------------------------------
// sc[c][t] = S[t][:] . C[:][c] for both SSMs. Grid 32 blocks, 256 threads.
// ---------------------------------------------------------------------------
__global__ __launch_bounds__(256) void sc_gemm(const float* __restrict__ Sws,
                                               const float* __restrict__ C1,
                                               const float* __restrict__ C2,
                                               float* __restrict__ sc1,
                                               float* __restrict__ sc2)
{
    const int ssm = blockIdx.x >> 4, tt = blockIdx.x & 15;
    const int t0 = tt << 5;
    const float* Cm = ssm ? C2 : C1;
    float* sc = ssm ? sc2 : sc1;
    const float* S = Sws + (size_t)ssm * (TT * 32);

    __shared__ float Ssh[32][33];
    __shared__ float Csh[32][132];
    const int tid = threadIdx.x;

    for (int idx = tid; idx < 1024; idx += 256) {
        int t = idx >> 5, j = idx & 31;
        Ssh[t][j] = S[(t0 + t) * 32 + j];
    }
    for (int idx = tid; idx < 4096; idx += 256)
        Csh[idx >> 7][idx & 127] = Cm[idx];
    __syncthreads();

    const int t = tid & 31, cg = tid >> 5;
    const int c0 = cg * 16;
    float sreg[32];
#pragma unroll
    for (int j = 0; j < 32; ++j) sreg[j] = Ssh[t][j];
    float acc[16];
#pragma unroll
    for (int k = 0; k < 16; ++k) acc[k] = 0.f;
#pragma unroll
    for (int j = 0; j < 32; ++j) {
        float4 c4a = *(const float4*)&Csh[j][c0];
        float4 c4b = *(const float4*)&Csh[j][c0 + 4];
        float4 c4c = *(const float4*)&Csh[j][c0 + 8];
        float4 c4d = *(const float4*)&Csh[j][c0 + 12];
        const float s = sreg[j];
        acc[0] += s * c4a.x; acc[1] += s * c4a.y; acc[2] += s * c4a.z; acc[3] += s * c4a.w;
        acc[4] += s * c4b.x; acc[5] += s * c4b.y; acc[6] += s * c4b.z; acc[7] += s * c4b.w;
        acc[8] += s * c4c.x; acc[9] += s * c4c.y; acc[10] += s * c4c.z; acc[11] += s * c4c.w;
        acc[12] += s * c4d.x; acc[13] += s * c4d.y; acc[14] += s * c4d.z; acc[15] += s * c4d.w;
    }
#pragma unroll
    for (int k = 0; k < 16; ++k) sc[(c0 + k) * TT + t0 + t] = acc[k];
}

// ---------------------------------------------------------------------------
// Host-side launch
// ---------------------------------------------------------------------------
extern "C" void kernel_launch(void* const* d_in, const int* in_sizes, int n_in,
                              void* d_out, int out_size, void* d_ws, size_t ws_size,
                              hipStream_t stream)
{
    (void)in_sizes; (void)n_in; (void)out_size; (void)ws_size;

    auto pf = [&](int i) { return (const float*)d_in[i]; };

    const float* x = pf(0);

    const size_t NT = (size_t)BB * CC * HH * TT;      // 33554432
    unsigned short* B0 = (unsigned short*)d_ws;
    unsigned short* B1 = B0 + NT;
    unsigned short* B2 = B1 + NT;
    unsigned short* wbf = B2 + NT;                    // 8 x 16384 bf16
    float* sc1 = (float*)(wbf + 8 * 16384);
    float* sc2 = sc1 + CC * TT;
    float* Sws = sc2 + CC * TT;                       // 2*512*32
    float* Mg = Sws + 2 * TT * 32;                    // 2 x 10 x 1024
    float* Fg = Mg + 2 * 10240;                       // 2 x 10 x 1024
    float* cpart = Fg + 2 * 10240;                    // 1024 x 1024 = 4MiB
    float* pavg = cpart + (size_t)1024 * 1024;        // 1024
    float* pmax = pavg + 1024;                        // 1024
    float* achan = pmax + 1024;                       // 1024
    float* sspat = achan + 1024;                      // 8*2*32768
    float* aspat = sspat + (size_t)BB * 2 * HW;       // 262144
    float* OUT = (float*)d_out;

    const dim3 blk(256);
    const int PW_GRID = 4096;
    const int DW_GRID = 8192;
    const int PIX_GRID = NPIX / 256;                  // 1024

    prep_weights<<<512, blk, 0, stream>>>(pf(1), pf(5), pf(8), pf(14),
                                          pf(22), pf(25), pf(31), pf(2), wbf);
    mat_powers<<<2, blk, 0, stream>>>(pf(16), pf(33), Mg, Fg);
    scan_apply<<<16, 64, 0, stream>>>(pf(17), pf(34), Mg, Fg, Sws);
    sc_gemm<<<32, blk, 0, stream>>>(Sws, pf(18), pf(35), sc1, sc2);

    // stem: x(f32) -> B0 (bf16)
    pw_mfma<64, 0, false, false, true, false, false, false><<<PW_GRID, blk, 0, stream>>>(
        x, wbf + 0, nullptr, B0, nullptr, nullptr);

    // Buffer rotation: dw: I->X,Y; pw1: X->I (b1, cpart); pw2: Y->X (b2, spool);
    // pw_ssm: reads I(b1),X(b2) -> writes Y.
    auto run_block = [&](int pb, int wslot, const float* scp, bool flip,
                         unsigned short* I, unsigned short* Xb, unsigned short* Yb) {
        if (flip)
            dw5x5_dual<true><<<DW_GRID, blk, 0, stream>>>(I, pf(pb + 0), pf(pb + 3), Xb, Yb);
        else
            dw5x5_dual<false><<<DW_GRID, blk, 0, stream>>>(I, pf(pb + 0), pf(pb + 3), Xb, Yb);
        pw_mfma<128, 1, false, true, false, false, true, false><<<PW_GRID, blk, 0, stream>>>(
            Xb, wbf + (size_t)wslot * 16384, pf(pb + 2), I, cpart, nullptr);
        pw_mfma<128, 1, false, true, false, false, false, true><<<PW_GRID, blk, 0, stream>>>(
            Yb, wbf + (size_t)(wslot + 1) * 16384, pf(pb + 5), Xb, nullptr, sspat);
        chan_reduce<<<1024, blk, 0, stream>>>(cpart, pavg, pmax);
        chan_mlp<<<8, blk, 0, stream>>>(pavg, pmax, pf(pb + 6), pf(pb + 7), achan);
        spat_conv<<<PIX_GRID, blk, 0, stream>>>(sspat, pf(pb + 8), aspat);
        pw_ssm<<<PW_GRID, blk, 0, stream>>>(I, wbf + (size_t)(wslot + 2) * 16384,
                                            pf(pb + 11), Xb, aspat, scp,
                                            pf(pb + 15), pf(pb + 16),
                                            achan, pf(pb + 9), Yb);
    };

    // block 1: (I,X,Y) = (B0,B1,B2) -> out B2; block 2: (B2,B0,B1) -> out B1
    run_block(4, 1, sc1, false, B0, B1, B2);
    run_block(21, 4, sc2, true, B2, B0, B1);

    // final: relu(bn(pw(flip(B1), w_out))) -> d_out (f32)
    pw_mfma<128, 1, true, true, false, true, false, false><<<PW_GRID, blk, 0, stream>>>(
        B1, wbf + 7 * 16384, pf(3), OUT, nullptr, nullptr);
}

// Round 15
// 622.212 us; speedup vs baseline: 1.0207x; 1.0207x over previous
//
#include <hip/hip_runtime.h>
#include <cstdint>
#include <cstddef>

#define EPSF 1e-5f

// Dims (fixed by the problem)
#define BB 8
#define CC 128
#define HH 64
#define TT 512
#define HW (HH*TT)          // 32768
#define NPIX (BB*HH*TT)     // 262144

__device__ __forceinline__ float rcpf(float x) { return __builtin_amdgcn_rcpf(x); }
__device__ __forceinline__ float sigf(float x) { return rcpf(1.f + __expf(-x)); }

// Branch-free erf (Abramowitz-Stegun 7.1.26, |err| <= 1.5e-7), rcp-based
__device__ __forceinline__ float erf_fast(float x) {
    float ax = fabsf(x);
    float t = rcpf(1.f + 0.3275911f * ax);
    float y = t * (0.254829592f + t * (-0.284496736f + t * (1.421413741f
               + t * (-1.453152027f + t * 1.061405429f))));
    float r = 1.f - y * __expf(-ax * ax);
    return copysignf(r, x);
}
__device__ __forceinline__ float geluf(float z) {
    return 0.5f * z * (1.f + erf_fast(z * 0.70710678118654752f));
}

// bf16 <-> f32 (RNE)
__device__ __forceinline__ unsigned short f2u(float f) {
    unsigned int u = __builtin_bit_cast(unsigned int, f);
    u += 0x7fffu + ((u >> 16) & 1u);
    return (unsigned short)(u >> 16);
}
__device__ __forceinline__ float u2f(unsigned short s) {
    return __builtin_bit_cast(float, (unsigned int)s << 16);
}
__device__ __forceinline__ float u2f_lo(unsigned x) {
    return __builtin_bit_cast(float, x << 16);
}
__device__ __forceinline__ float u2f_hi(unsigned x) {
    return __builtin_bit_cast(float, x & 0xffff0000u);
}

typedef __attribute__((ext_vector_type(8))) short bf16x8;
typedef __attribute__((ext_vector_type(4))) float f32x4;

// X-tile LDS offset: +8 shorts (16B) pad every 8 rows breaks the structural
// 8-way bank conflict of 16B-aligned row strides; keeps 16B alignment.
#define XO(t, CSTR) ((t) * (CSTR) + ((t) >> 3) * 8)

// ---------------------------------------------------------------------------
// Weight prep: 8 pw weight matrices f32 -> bf16 in MFMA-FRAGMENT-SHUFFLED
// order: per slot [og(4)][f(2)][ks(KS)][lane(64)][e(8)].
// slot0: w_in (CIN=64), 1:b1_pwa 2:b1_pwb 3:b1_d1p 4:b2_pwa 5:b2_pwb
// 6:b2_d1p 7:w_out (CIN=128).
// ---------------------------------------------------------------------------
__global__ __launch_bounds__(256) void prep_weights(const float* __restrict__ s0,
                                                    const float* __restrict__ s1,
                                                    const float* __restrict__ s2,
                                                    const float* __restrict__ s3,
                                                    const float* __restrict__ s4,
                                                    const float* __restrict__ s5,
                                                    const float* __restrict__ s6,
                                                    const float* __restrict__ s7,
                                                    unsigned short* __restrict__ wbf)
{
    int gid = blockIdx.x * 256 + threadIdx.x;     // 0..131071
    int slot = gid >> 14, idx = gid & 16383;
    const float* srcs[8] = {s0, s1, s2, s3, s4, s5, s6, s7};
    const int CIN = (slot == 0) ? 64 : 128;
    const int KS = CIN / 32;
    float v = 0.f;
    if (slot != 0 || idx < 8192) {
        int e = idx & 7, lane = (idx >> 3) & 63;
        int rest = idx >> 9;
        int ks = rest % KS, f = (rest / KS) & 1, og = rest / (2 * KS);
        int row = og * 32 + f * 16 + (lane & 15);
        int col = ks * 32 + (lane >> 4) * 8 + e;
        v = srcs[slot][row * CIN + col];
    }
    wbf[gid] = f2u(v);
}

// ---------------------------------------------------------------------------
// Pointwise conv via bf16 MFMA. W fragments coalesced into registers;
// X tile transposed in LDS (XO padding). CPOOL: per-block channel-pool
// partials -> cpart[(b*128+row)*1024 + slot] (sums) / +512 (maxes).
// SPOOL: per-pixel mean/max -> sspat. Grid 4096, 256 threads.
// ---------------------------------------------------------------------------
template<int CIN, int ACT, bool FLIP, bool BN, bool INF32, bool OUTF32, bool CPOOL, bool SPOOL>
__global__ __launch_bounds__(256) void pw_mfma(const void* __restrict__ inv,
                                               const unsigned short* __restrict__ Wb,
                                               const float* __restrict__ bnp,
                                               void* __restrict__ outv,
                                               float* __restrict__ cpart,
                                               float* __restrict__ sspat)
{
    constexpr int CSTR = CIN + 8;
    constexpr int KS = CIN / 32;
    constexpr int CP = CIN / 32;          // c-rows per staging thread
    __shared__ unsigned short Xl[64 * CSTR + 64];
    __shared__ float bns[128], bnh[128];
    __shared__ float spsum[4][64], spmax[4][64];

    const int tid = threadIdx.x;
    const int bh = blockIdx.x >> 3, tt = blockIdx.x & 7;
    const int b = bh >> 6, h = bh & 63;
    const int t0 = tt << 6;

    const int lane = tid & 63, wv = tid >> 6;
    const int lanel = lane & 15, laneh = lane >> 4;
    const int ob = wv * 32;

    // ---- W fragments -> registers (coalesced: lane*8 contiguous) ----
    bf16x8 afr[2][KS];
#pragma unroll
    for (int f = 0; f < 2; ++f)
#pragma unroll
        for (int ks = 0; ks < KS; ++ks)
            afr[f][ks] = *(const bf16x8*)&Wb[(size_t)wv * (2 * KS * 512)
                                             + (f * KS + ks) * 512 + lane * 8];

    if (BN && tid < 128) {
        float g = bnp[tid], be = bnp[CC + tid], m = bnp[2 * CC + tid], v = bnp[3 * CC + tid];
        float s = g * rsqrtf(v + EPSF);
        bns[tid] = s; bnh[tid] = be - m * s;
    }

    // ---- stage X transposed: Xl[t][c] ----
    {
        const int s = tid & 7, g = tid >> 3;
        const int tl0 = s * 8;
        const int c0 = g * CP;
        unsigned short vals[CP][8];
#pragma unroll
        for (int i = 0; i < CP; ++i) {
            const size_t rowbase = ((size_t)(b * CIN + c0 + i) * HH + h) * TT;
            const int tb = FLIP ? (504 - t0 - tl0) : (t0 + tl0);
            if (INF32) {
                const float* pf32 = (const float*)inv;
                float4 u0 = *(const float4*)&pf32[rowbase + tb];
                float4 u1 = *(const float4*)&pf32[rowbase + tb + 4];
                float tmp[8] = {u0.x, u0.y, u0.z, u0.w, u1.x, u1.y, u1.z, u1.w};
#pragma unroll
                for (int j = 0; j < 8; ++j) vals[i][j] = f2u(tmp[FLIP ? 7 - j : j]);
            } else {
                const unsigned short* pb = (const unsigned short*)inv;
                unsigned short tmp[8];
                *(uint4*)tmp = *(const uint4*)&pb[rowbase + tb];
#pragma unroll
                for (int j = 0; j < 8; ++j) vals[i][j] = tmp[FLIP ? 7 - j : j];
            }
        }
#pragma unroll
        for (int j = 0; j < 8; ++j) {
            unsigned short* dst = &Xl[XO(tl0 + j, CSTR) + c0];
            if (CP == 4) {
                uint2 pk;
                pk.x = (unsigned)vals[0][j] | ((unsigned)vals[1][j] << 16);
                pk.y = (unsigned)vals[2][j] | ((unsigned)vals[3][j] << 16);
                *(uint2*)dst = pk;
            } else {
                *(unsigned int*)dst = (unsigned)vals[0][j] | ((unsigned)vals[1][j] << 16);
            }
        }
    }
    __syncthreads();

    // ---- MFMA: wave tile 32 o x 64 t ----
    f32x4 acc[2][4];
#pragma unroll
    for (int f = 0; f < 2; ++f)
#pragma unroll
        for (int tf = 0; tf < 4; ++tf) acc[f][tf] = (f32x4){0.f, 0.f, 0.f, 0.f};

#pragma unroll
    for (int ks = 0; ks < KS; ++ks) {
        const int kb = ks * 32 + laneh * 8;
#pragma unroll
        for (int tf = 0; tf < 4; ++tf) {
            bf16x8 bb = *(const bf16x8*)&Xl[XO(tf * 16 + lanel, CSTR) + kb];
            acc[0][tf] = __builtin_amdgcn_mfma_f32_16x16x32_bf16(afr[0][ks], bb, acc[0][tf], 0, 0, 0);
            acc[1][tf] = __builtin_amdgcn_mfma_f32_16x16x32_bf16(afr[1][ks], bb, acc[1][tf], 0, 0, 0);
        }
    }

    // ---- epilogue: BN + act + store (+ fused pools) ----
    const size_t obase = ((size_t)(b * CC) * HH + h) * TT;
    const int slot = h * 8 + tt;                  // 0..511
    float cs[4], cm[4];
    if (SPOOL) {
#pragma unroll
        for (int tf = 0; tf < 4; ++tf) { cs[tf] = 0.f; cm[tf] = -3.4e38f; }
    }
#pragma unroll
    for (int f = 0; f < 2; ++f) {
#pragma unroll
        for (int r = 0; r < 4; ++r) {
            const int row = ob + f * 16 + laneh * 4 + r;
            const float s = BN ? bns[row] : 1.f;
            const float sh = BN ? bnh[row] : 0.f;
            float rs = 0.f, rm = -3.4e38f;
#pragma unroll
            for (int tf = 0; tf < 4; ++tf) {
                float v = acc[f][tf][r] * s + sh;
                if (ACT == 1) v = fmaxf(v, 0.f);
                if (ACT == 2) v = sigf(v);
                size_t oidx = obase + (size_t)row * HW + t0 + tf * 16 + lanel;
                if (OUTF32) ((float*)outv)[oidx] = v;
                else ((unsigned short*)outv)[oidx] = f2u(v);
                if (CPOOL) { rs += v; rm = fmaxf(rm, v); }
                if (SPOOL) { cs[tf] += v; cm[tf] = fmaxf(cm[tf], v); }
            }
            if (CPOOL) {
                rs += __shfl_xor(rs, 1); rm = fmaxf(rm, __shfl_xor(rm, 1));
                rs += __shfl_xor(rs, 2); rm = fmaxf(rm, __shfl_xor(rm, 2));
                rs += __shfl_xor(rs, 4); rm = fmaxf(rm, __shfl_xor(rm, 4));
                rs += __shfl_xor(rs, 8); rm = fmaxf(rm, __shfl_xor(rm, 8));
                if (lanel == 0) {
                    cpart[((size_t)(b * CC + row)) * 1024 + slot] = rs;
                    cpart[((size_t)(b * CC + row)) * 1024 + 512 + slot] = rm;
                }
            }
        }
    }
    if (SPOOL) {
#pragma unroll
        for (int tf = 0; tf < 4; ++tf) {
            cs[tf] += __shfl_xor(cs[tf], 16); cm[tf] = fmaxf(cm[tf], __shfl_xor(cm[tf], 16));
            cs[tf] += __shfl_xor(cs[tf], 32); cm[tf] = fmaxf(cm[tf], __shfl_xor(cm[tf], 32));
        }
        if (laneh == 0) {
#pragma unroll
            for (int tf = 0; tf < 4; ++tf) {
                spsum[wv][tf * 16 + lanel] = cs[tf];
                spmax[wv][tf * 16 + lanel] = cm[tf];
            }
        }
        __syncthreads();
        if (tid < 64) {
            float su = spsum[0][tid] + spsum[1][tid] + spsum[2][tid] + spsum[3][tid];
            float mx = fmaxf(fmaxf(spmax[0][tid], spmax[1][tid]),
                             fmaxf(spmax[2][tid], spmax[3][tid]));
            const int sp = h * TT + t0 + tid;
            sspat[((size_t)b * 2) * HW + sp] = su * (1.f / 128.f);
            sspat[((size_t)b * 2 + 1) * HW + sp] = mx;
        }
    }
}

// ---------------------------------------------------------------------------
// chan_reduce: one block per (b,c); contiguous partials, coalesced + LDS
// tree. Grid 1024 x 256.
// ---------------------------------------------------------------------------
__global__ __launch_bounds__(256) void chan_reduce(const float* __restrict__ cpart,
                                                   float* __restrict__ pavg,
                                                   float* __restrict__ pmax)
{
    __shared__ float ss[256], sm[256];
    const int bc = blockIdx.x, tid = threadIdx.x;
    const float* p = cpart + (size_t)bc * 1024;
    float s = p[tid] + p[tid + 256];
    float m = fmaxf(p[512 + tid], p[768 + tid]);
    ss[tid] = s; sm[tid] = m;
    __syncthreads();
    for (int w = 128; w > 0; w >>= 1) {
        if (tid < w) { ss[tid] += ss[tid + w]; sm[tid] = fmaxf(sm[tid], sm[tid + w]); }
        __syncthreads();
    }
    if (tid == 0) { pavg[bc] = ss[0] * (1.f / (float)HW); pmax[bc] = sm[0]; }
}

// ---------------------------------------------------------------------------
// Channel-attention MLP on precomputed pools. Grid 8 x 256.
// ---------------------------------------------------------------------------
__global__ __launch_bounds__(256) void chan_mlp(const float* __restrict__ pavg,
                                                const float* __restrict__ pmax,
                                                const float* __restrict__ w1,
                                                const float* __restrict__ w2,
                                                float* __restrict__ a)
{
    __shared__ float ua[128], um[128], hid[16];
    const int b = blockIdx.x, tid = threadIdx.x;
    if (tid < 128) { ua[tid] = pavg[b * 128 + tid]; um[tid] = pmax[b * 128 + tid]; }
    __syncthreads();
    if (tid < 16) {
        int mm = tid >> 1, path = tid & 1;
        const float* u = path ? um : ua;
        float acc = 0.f;
#pragma unroll
        for (int cc = 0; cc < 128; ++cc) acc += u[cc] * w1[mm * 128 + cc];
        hid[tid] = fmaxf(acc, 0.f);
    }
    __syncthreads();
    if (tid < 128) {
        float acc = 0.f;
#pragma unroll
        for (int mm = 0; mm < 8; ++mm) acc += (hid[2 * mm] + hid[2 * mm + 1]) * w2[tid * 8 + mm];
        a[b * 128 + tid] = sigf(acc);
    }
}

// ---------------------------------------------------------------------------
// FUSED: staging computes cb = b1^2*achan then dw1x3 -> X tile; pw(d1p)+BN+
// sigmoid via MFMA; SSM+GELU; channel-LN; * sigmoid(b2^2*aspat).
// b2 is bounced through the retired X LDS tile (coalesced reads).
// Grid 4096, 256 threads.
// ---------------------------------------------------------------------------
__global__ __launch_bounds__(256) void pw_ssm(const unsigned short* __restrict__ b1t,
                                              const unsigned short* __restrict__ Wb,
                                              const float* __restrict__ bnp,
                                              const unsigned short* __restrict__ b2t,
                                              const float* __restrict__ aspat,
                                              const float* __restrict__ sc,
                                              const float* __restrict__ Dv,
                                              const float* __restrict__ ln,
                                              const float* __restrict__ ach,
                                              const float* __restrict__ d1w,
                                              unsigned short* __restrict__ outp)
{
    constexpr int CIN = 128;
    constexpr int CSTR = CIN + 8;
    __shared__ unsigned short Xl[64 * CSTR + 64];   // reused as b2 tile later
    __shared__ float bns[128], bnh[128];
    __shared__ float sDv[128], slnw[128], slnb[128];
    __shared__ float psum[4][64], psq[4][64];
    __shared__ float smu[64], srstd[64], sas[64];

    const int tid = threadIdx.x;
    const int bh = blockIdx.x >> 3, tt = blockIdx.x & 7;
    const int b = bh >> 6, h = bh & 63;
    const int t0 = tt << 6;

    const int lane = tid & 63, wv = tid >> 6;
    const int lanel = lane & 15, laneh = lane >> 4;
    const int ob = wv * 32;
    const size_t obase = ((size_t)(b * CC) * HH + h) * TT;

    bf16x8 afr[2][4];
#pragma unroll
    for (int f = 0; f < 2; ++f)
#pragma unroll
        for (int ks = 0; ks < 4; ++ks)
            afr[f][ks] = *(const bf16x8*)&Wb[(size_t)wv * 4096 + (f * 4 + ks) * 512 + lane * 8];

    if (tid < 128) {
        float g = bnp[tid], be = bnp[CC + tid], m = bnp[2 * CC + tid], v = bnp[3 * CC + tid];
        float s = g * rsqrtf(v + EPSF);
        bns[tid] = s; bnh[tid] = be - m * s;
        sDv[tid] = Dv[tid]; slnw[tid] = ln[tid]; slnb[tid] = ln[CC + tid];
    }
    if (tid < 64) sas[tid] = aspat[((size_t)b * HH + h) * TT + t0 + tid];

    {
        const int s = tid & 7, g = tid >> 3;
        const int tl0 = s * 8;
        const int c0 = g * 4;
        const int tg = t0 + tl0;
        unsigned short vals[4][8];
#pragma unroll
        for (int i = 0; i < 4; ++i) {
            const int c = c0 + i;
            const unsigned short* p = b1t + ((size_t)(b * CC + c) * HH + h) * TT;
            const float av = ach[b * CC + c];
            const float w0 = d1w[c * 3 + 0], w1 = d1w[c * 3 + 1], w2 = d1w[c * 3 + 2];
            unsigned short raw2[8];
            *(uint4*)raw2 = *(const uint4*)&p[tg];
            float cb[10];
            cb[0] = 0.f;
            if (tg > 0) { float l = u2f(p[tg - 1]); cb[0] = l * l * av; }
            cb[9] = 0.f;
            if (tg + 8 < TT) { float rr = u2f(p[tg + 8]); cb[9] = rr * rr * av; }
#pragma unroll
            for (int j = 0; j < 8; ++j) { float x = u2f(raw2[j]); cb[j + 1] = x * x * av; }
#pragma unroll
            for (int j = 0; j < 8; ++j)
                vals[i][j] = f2u(cb[j] * w0 + cb[j + 1] * w1 + cb[j + 2] * w2);
        }
#pragma unroll
        for (int j = 0; j < 8; ++j) {
            uint2 pk;
            pk.x = (unsigned)vals[0][j] | ((unsigned)vals[1][j] << 16);
            pk.y = (unsigned)vals[2][j] | ((unsigned)vals[3][j] << 16);
            *(uint2*)&Xl[XO(tl0 + j, CSTR) + c0] = pk;
        }
    }
    __syncthreads();

    f32x4 acc[2][4];
#pragma unroll
    for (int f = 0; f < 2; ++f)
#pragma unroll
        for (int tf = 0; tf < 4; ++tf) acc[f][tf] = (f32x4){0.f, 0.f, 0.f, 0.f};

#pragma unroll
    for (int ks = 0; ks < 4; ++ks) {
        const int kb = ks * 32 + laneh * 8;
#pragma unroll
        for (int tf = 0; tf < 4; ++tf) {
            bf16x8 bb = *(const bf16x8*)&Xl[XO(tf * 16 + lanel, CSTR) + kb];
            acc[0][tf] = __builtin_amdgcn_mfma_f32_16x16x32_bf16(afr[0][ks], bb, acc[0][tf], 0, 0, 0);
            acc[1][tf] = __builtin_amdgcn_mfma_f32_16x16x32_bf16(afr[1][ks], bb, acc[1][tf], 0, 0, 0);
        }
    }

    float ps[4] = {0.f, 0.f, 0.f, 0.f}, pq[4] = {0.f, 0.f, 0.f, 0.f};
#pragma unroll
    for (int f = 0; f < 2; ++f) {
#pragma unroll
        for (int r = 0; r < 4; ++r) {
            const int row = ob + f * 16 + laneh * 4 + r;
            const float s = bns[row], sh = bnh[row], dv = sDv[row];
#pragma unroll
            for (int tf = 0; tf < 4; ++tf) {
                const int col = tf * 16 + lanel;
                float x = sigf(acc[f][tf][r] * s + sh);
                float z = sc[row * TT + t0 + col] + x * dv;
                float o = x + geluf(z);
                acc[f][tf][r] = o;
                ps[tf] += o; pq[tf] += o * o;
            }
        }
    }
#pragma unroll
    for (int tf = 0; tf < 4; ++tf) {
        ps[tf] += __shfl_xor(ps[tf], 16);
        ps[tf] += __shfl_xor(ps[tf], 32);
        pq[tf] += __shfl_xor(pq[tf], 16);
        pq[tf] += __shfl_xor(pq[tf], 32);
    }
    if (laneh == 0) {
#pragma unroll
        for (int tf = 0; tf < 4; ++tf) {
            psum[wv][tf * 16 + lanel] = ps[tf];
            psq[wv][tf * 16 + lanel] = pq[tf];
        }
    }
    __syncthreads();   // also: all Xl reads (MFMA) complete -> safe to reuse

    // ---- stage b2 tile into retired Xl: [128 rows][68 stride] bf16 ----
    {
        const int s = tid & 7, g = tid >> 3;     // col0 = s*8, rows g*4+i
#pragma unroll
        for (int i = 0; i < 4; ++i) {
            uint4 v = *(const uint4*)&b2t[obase + (size_t)(g * 4 + i) * HW + t0 + s * 8];
            *(uint4*)&Xl[(g * 4 + i) * 68 + s * 8] = v;
        }
    }
    if (tid < 64) {
        float su = psum[0][tid] + psum[1][tid] + psum[2][tid] + psum[3][tid];
        float qu = psq[0][tid] + psq[1][tid] + psq[2][tid] + psq[3][tid];
        float mu = su * (1.f / 128.f);
        float var = qu * (1.f / 128.f) - mu * mu;
        smu[tid] = mu; srstd[tid] = rsqrtf(var + EPSF);
    }
    __syncthreads();

    // ---- LN + spatial-branch multiply + store bf16 ----
#pragma unroll
    for (int f = 0; f < 2; ++f) {
#pragma unroll
        for (int r = 0; r < 4; ++r) {
            const int row = ob + f * 16 + laneh * 4 + r;
            const float lw = slnw[row], lb = slnb[row];
#pragma unroll
            for (int tf = 0; tf < 4; ++tf) {
                const int col = tf * 16 + lanel;
                float val = (acc[f][tf][r] - smu[col]) * srstd[col] * lw + lb;
                float bv = u2f(Xl[row * 68 + col]);
                float sb = sigf(bv * bv * sas[col]);
                outp[obase + (size_t)row * HW + t0 + col] = f2u(val * sb);
            }
        }
    }
}

// ---------------------------------------------------------------------------
// Depthwise 5x5 'same' conv (bf16 in/out, f32 compute), dual weight sets.
// Register-blocked 32h x 64t tile, vectorized staging ([36][84] f32 tile,
// 360 uint4 segment loads). Col map: LDS col k <-> global t0-8+k; output t
// needs col 6+t+dj. Grid 16384 x 256.  (Round-12 version: the round-13
// 2t-per-thread re-block regressed -- VGPR/LDS pressure outweighed the
// LDS-read sharing.)
// ---------------------------------------------------------------------------
template<bool FLIP>
__global__ __launch_bounds__(256) void dw5x5_dual(const unsigned short* __restrict__ in,
                                                  const float* __restrict__ wa,
                                                  const float* __restrict__ wb,
                                                  unsigned short* __restrict__ oa,
                                                  unsigned short* __restrict__ ob)
{
    __shared__ float tile[36][84];
    __shared__ float wla[25], wlb[25];
    const int tid = threadIdx.x;
    const int bc = blockIdx.x >> 4;
    const int tl4 = blockIdx.x & 15;
    const int ht = tl4 >> 3, tt = tl4 & 7;
    const int h0 = ht << 5, t0 = tt << 6;
    const int c = bc & (CC - 1);
    const unsigned short* base = in + (size_t)bc * HW;

    if (tid < 25) { wla[tid] = wa[c * 25 + tid]; wlb[tid] = wb[c * 25 + tid]; }
    // ---- vectorized staging: 36 rows x 10 segments of 8 shorts ----
    for (int task = tid; task < 360; task += 256) {
        const int r = task / 10, sg = task - r * 10;
        const int grow = h0 - 2 + r;
        const int gcol = t0 - 8 + sg * 8;
        float v[8];
        if (grow >= 0 && grow < HH && gcol >= 0 && gcol <= TT - 8) {
            const int gc = FLIP ? (TT - 8 - gcol) : gcol;
            uint4 u = *(const uint4*)&base[grow * TT + gc];
            if (FLIP) {
                uint4 rv;
                rv.x = (u.w >> 16) | (u.w << 16);
                rv.y = (u.z >> 16) | (u.z << 16);
                rv.z = (u.y >> 16) | (u.y << 16);
                rv.w = (u.x >> 16) | (u.x << 16);
                u = rv;
            }
            v[0] = u2f_lo(u.x); v[1] = u2f_hi(u.x);
            v[2] = u2f_lo(u.y); v[3] = u2f_hi(u.y);
            v[4] = u2f_lo(u.z); v[5] = u2f_hi(u.z);
            v[6] = u2f_lo(u.w); v[7] = u2f_hi(u.w);
        } else {
#pragma unroll
            for (int j = 0; j < 8; ++j) v[j] = 0.f;
        }
        float* dst = &tile[r][sg * 8];
        *(float4*)dst = (float4){v[0], v[1], v[2], v[3]};
        *(float4*)(dst + 4) = (float4){v[4], v[5], v[6], v[7]};
    }
    __syncthreads();

    const int w = tid >> 6, lane = tid & 63;
    const int r0 = w * 8;

    float sa[8], sb[8];
#pragma unroll
    for (int o = 0; o < 8; ++o) { sa[o] = 0.f; sb[o] = 0.f; }

#pragma unroll
    for (int dj = 0; dj < 5; ++dj) {
        float val[12];
#pragma unroll
        for (int k = 0; k < 12; ++k) val[k] = tile[r0 + k][6 + lane + dj];
#pragma unroll
        for (int di = 0; di < 5; ++di) {
            const float wva = wla[di * 5 + dj], wvb = wlb[di * 5 + dj];
#pragma unroll
            for (int o = 0; o < 8; ++o) {
                sa[o] += val[o + di] * wva;
                sb[o] += val[o + di] * wvb;
            }
        }
    }

    const size_t obase = (size_t)bc * HW + (size_t)(h0 + r0) * TT + t0 + lane;
#pragma unroll
    for (int o = 0; o < 8; ++o) {
        oa[obase + (size_t)o * TT] = f2u(sa[o]);
        ob[obase + (size_t)o * TT] = f2u(sb[o]);
    }
}

// ---------------------------------------------------------------------------
// 7x7 conv on 2-ch pooled map + sigmoid (f32). Grid 1024x256.
// ---------------------------------------------------------------------------
__global__ __launch_bounds__(256) void spat_conv(const float* __restrict__ s,
                                                 const float* __restrict__ w,
                                                 float* __restrict__ a)
{
    __shared__ float wl[98];
    const int tid = threadIdx.x;
    if (tid < 98) wl[tid] = w[tid];
    __syncthreads();
    const int pix = blockIdx.x * 256 + tid;
    const int t = pix & 511, h = (pix >> 9) & 63, b = pix >> 15;
    float acc = 0.f;
#pragma unroll
    for (int ch = 0; ch < 2; ++ch) {
        const float* sp = s + ((size_t)b * 2 + ch) * HW;
#pragma unroll
        for (int di = 0; di < 7; ++di) {
            int hh = h + di - 3;
            if (hh < 0 || hh >= HH) continue;
#pragma unroll
            for (int dj = 0; dj < 7; ++dj) {
                int t2 = t + dj - 3;
                if (t2 < 0 || t2 >= TT) continue;
                acc += sp[hh * TT + t2] * wl[ch * 49 + di * 7 + dj];
            }
        }
    }
    a[pix] = sigf(acc);
}

// ---------------------------------------------------------------------------
// mat_powers: per SSM, compute M^(2^k) and F_(2^k) for k=0..9. Grid 2 x 256.
// ---------------------------------------------------------------------------
__global__ __launch_bounds__(256) void mat_powers(const float* __restrict__ A1,
                                                  const float* __restrict__ A2,
                                                  float* __restrict__ Mg,
                                                  float* __restrict__ Fg)
{
    const float* A = blockIdx.x ? A2 : A1;
    float* Mo = Mg + (size_t)blockIdx.x * 10240;
    float* Fo = Fg + (size_t)blockIdx.x * 10240;
    __shared__ float Mc[1024], Fc[1024], Mn[1024], Fn[1024];
    const int tid = threadIdx.x;

    for (int idx = tid; idx < 1024; idx += 256) {
        int k = idx >> 5, j = idx & 31;
        Mc[idx] = A[j * 32 + k];
        Fc[idx] = (k == j) ? 1.f : 0.f;
    }
    __syncthreads();
    for (int k = 0; k < 10; ++k) {
        for (int idx = tid; idx < 1024; idx += 256) {
            Mo[k * 1024 + idx] = Mc[idx];
            Fo[k * 1024 + idx] = Fc[idx];
        }
        if (k == 9) break;
        for (int idx = tid; idx < 1024; idx += 256) {
            int r = idx >> 5, cc = idx & 31;
            float am = 0.f, af = 0.f;
#pragma unroll
            for (int m = 0; m < 32; ++m) {
                am += Mc[r * 32 + m] * Mc[m * 32 + cc];
                af += Mc[r * 32 + m] * Fc[m * 32 + cc];
            }
            Mn[idx] = am;
            Fn[idx] = Fc[idx] + af;
        }
        __syncthreads();
        for (int idx = tid; idx < 1024; idx += 256) { Mc[idx] = Mn[idx]; Fc[idx] = Fn[idx]; }
        __syncthreads();
    }
}

// ---------------------------------------------------------------------------
// scan_apply: S[t] = B * F_{t+1} via bit-decomposition. Grid 16 x 64.
// ---------------------------------------------------------------------------
__global__ __launch_bounds__(64) void scan_apply(const float* __restrict__ B1,
                                                 const float* __restrict__ B2,
                                                 const float* __restrict__ Mg,
                                                 const float* __restrict__ Fg,
                                                 float* __restrict__ Sws)
{
    __shared__ float Ml[5][1024], Fl[5][1024];   // 40KB
    const int ssm = blockIdx.x >> 3;
    const int tb = blockIdx.x & 7;
    const float* Bv = ssm ? B2 : B1;
    const float* Mi = Mg + (size_t)ssm * 10240;
    const float* Fi = Fg + (size_t)ssm * 10240;
    float* Sg = Sws + (size_t)ssm * (TT * 32);
    const int tid = threadIdx.x;
    const int t = tb * 64 + tid;
    const int n = t + 1;

    float z[32], v[32];
#pragma unroll
    for (int j = 0; j < 32; ++j) { z[j] = 0.f; v[j] = Bv[j]; }

    for (int ph = 0; ph < 2; ++ph) {
        __syncthreads();
        for (int idx = tid; idx < 5120; idx += 64) {
            (&Ml[0][0])[idx] = Mi[ph * 5120 + idx];
            (&Fl[0][0])[idx] = Fi[ph * 5120 + idx];
        }
        __syncthreads();
        for (int kk = 0; kk < 5; ++kk) {
            const int k = ph * 5 + kk;
            if (n & (1 << k)) {
                float zn[32], vn[32];
#pragma unroll
                for (int j = 0; j < 32; ++j) { zn[j] = z[j]; vn[j] = 0.f; }
#pragma unroll
                for (int m = 0; m < 32; ++m) {
                    const float vm = v[m];
                    const float* fr = &Fl[kk][m * 32];
                    const float* mr = &Ml[kk][m * 32];
#pragma unroll
                    for (int j = 0; j < 32; ++j) {
                        zn[j] += vm * fr[j];
                        vn[j] += vm * mr[j];
                    }
                }
#pragma unroll
                for (int j = 0; j < 32; ++j) { z[j] = zn[j]; v[j] = vn[j]; }
            }
        }
    }
#pragma unroll
    for (int j = 0; j < 32; ++j) Sg[t * 32 + j] = z[j];
}

// ---------------------------------------------------------------------------
// sc[c][t] = S[t][:] . C[:][c] for both SSMs. Grid 32 blocks, 256 threads.
// ---------------------------------------------------------------------------
__global__ __launch_bounds__(256) void sc_gemm(const float* __restrict__ Sws,
                                               const float* __restrict__ C1,
                                               const float* __restrict__ C2,
                                               float* __restrict__ sc1,
                                               float* __restrict__ sc2)
{
    const int ssm = blockIdx.x >> 4, tt = blockIdx.x & 15;
    const int t0 = tt << 5;
    const float* Cm = ssm ? C2 : C1;
    float* sc = ssm ? sc2 : sc1;
    const float* S = Sws + (size_t)ssm * (TT * 32);

    __shared__ float Ssh[32][33];
    __shared__ float Csh[32][132];
    const int tid = threadIdx.x;

    for (int idx = tid; idx < 1024; idx += 256) {
        int t = idx >> 5, j = idx & 31;
        Ssh[t][j] = S[(t0 + t) * 32 + j];
    }
    for (int idx = tid; idx < 4096; idx += 256)
        Csh[idx >> 7][idx & 127] = Cm[idx];
    __syncthreads();

    const int t = tid & 31, cg = tid >> 5;
    const int c0 = cg * 16;
    float sreg[32];
#pragma unroll
    for (int j = 0; j < 32; ++j) sreg[j] = Ssh[t][j];
    float acc[16];
#pragma unroll
    for (int k = 0; k < 16; ++k) acc[k] = 0.f;
#pragma unroll
    for (int j = 0; j < 32; ++j) {
        float4 c4a = *(const float4*)&Csh[j][c0];
        float4 c4b = *(const float4*)&Csh[j][c0 + 4];
        float4 c4c = *(const float4*)&Csh[j][c0 + 8];
        float4 c4d = *(const float4*)&Csh[j][c0 + 12];
        const float s = sreg[j];
        acc[0] += s * c4a.x; acc[1] += s * c4a.y; acc[2] += s * c4a.z; acc[3] += s * c4a.w;
        acc[4] += s * c4b.x; acc[5] += s * c4b.y; acc[6] += s * c4b.z; acc[7] += s * c4b.w;
        acc[8] += s * c4c.x; acc[9] += s * c4c.y; acc[10] += s * c4c.z; acc[11] += s * c4c.w;
        acc[12] += s * c4d.x; acc[13] += s * c4d.y; acc[14] += s * c4d.z; acc[15] += s * c4d.w;
    }
#pragma unroll
    for (int k = 0; k < 16; ++k) sc[(c0 + k) * TT + t0 + t] = acc[k];
}

// ---------------------------------------------------------------------------
// Host-side launch
// ---------------------------------------------------------------------------
extern "C" void kernel_launch(void* const* d_in, const int* in_sizes, int n_in,
                              void* d_out, int out_size, void* d_ws, size_t ws_size,
                              hipStream_t stream)
{
    (void)in_sizes; (void)n_in; (void)out_size; (void)ws_size;

    auto pf = [&](int i) { return (const float*)d_in[i]; };

    const float* x = pf(0);

    const size_t NT = (size_t)BB * CC * HH * TT;      // 33554432
    unsigned short* B0 = (unsigned short*)d_ws;
    unsigned short* B1 = B0 + NT;
    unsigned short* B2 = B1 + NT;
    unsigned short* wbf = B2 + NT;                    // 8 x 16384 bf16
    float* sc1 = (float*)(wbf + 8 * 16384);
    float* sc2 = sc1 + CC * TT;
    float* Sws = sc2 + CC * TT;                       // 2*512*32
    float* Mg = Sws + 2 * TT * 32;                    // 2 x 10 x 1024
    float* Fg = Mg + 2 * 10240;                       // 2 x 10 x 1024
    float* cpart = Fg + 2 * 10240;                    // 1024 x 1024 = 4MiB
    float* pavg = cpart + (size_t)1024 * 1024;        // 1024
    float* pmax = pavg + 1024;                        // 1024
    float* achan = pmax + 1024;                       // 1024
    float* sspat = achan + 1024;                      // 8*2*32768
    float* aspat = sspat + (size_t)BB * 2 * HW;       // 262144
    float* OUT = (float*)d_out;

    const dim3 blk(256);
    const int PW_GRID = 4096;
    const int DW_GRID = 16384;
    const int PIX_GRID = NPIX / 256;                  // 1024

    prep_weights<<<512, blk, 0, stream>>>(pf(1), pf(5), pf(8), pf(14),
                                          pf(22), pf(25), pf(31), pf(2), wbf);
    mat_powers<<<2, blk, 0, stream>>>(pf(16), pf(33), Mg, Fg);
    scan_apply<<<16, 64, 0, stream>>>(pf(17), pf(34), Mg, Fg, Sws);
    sc_gemm<<<32, blk, 0, stream>>>(Sws, pf(18), pf(35), sc1, sc2);

    // stem: x(f32) -> B0 (bf16)
    pw_mfma<64, 0, false, false, true, false, false, false><<<PW_GRID, blk, 0, stream>>>(
        x, wbf + 0, nullptr, B0, nullptr, nullptr);

    // Buffer rotation: dw: I->X,Y; pw1: X->I (b1, cpart); pw2: Y->X (b2, spool);
    // pw_ssm: reads I(b1),X(b2) -> writes Y.
    auto run_block = [&](int pb, int wslot, const float* scp, bool flip,
                         unsigned short* I, unsigned short* Xb, unsigned short* Yb) {
        if (flip)
            dw5x5_dual<true><<<DW_GRID, blk, 0, stream>>>(I, pf(pb + 0), pf(pb + 3), Xb, Yb);
        else
            dw5x5_dual<false><<<DW_GRID, blk, 0, stream>>>(I, pf(pb + 0), pf(pb + 3), Xb, Yb);
        pw_mfma<128, 1, false, true, false, false, true, false><<<PW_GRID, blk, 0, stream>>>(
            Xb, wbf + (size_t)wslot * 16384, pf(pb + 2), I, cpart, nullptr);
        pw_mfma<128, 1, false, true, false, false, false, true><<<PW_GRID, blk, 0, stream>>>(
            Yb, wbf + (size_t)(wslot + 1) * 16384, pf(pb + 5), Xb, nullptr, sspat);
        chan_reduce<<<1024, blk, 0, stream>>>(cpart, pavg, pmax);
        chan_mlp<<<8, blk, 0, stream>>>(pavg, pmax, pf(pb + 6), pf(pb + 7), achan);
        spat_conv<<<PIX_GRID, blk, 0, stream>>>(sspat, pf(pb + 8), aspat);
        pw_ssm<<<PW_GRID, blk, 0, stream>>>(I, wbf + (size_t)(wslot + 2) * 16384,
                                            pf(pb + 11), Xb, aspat, scp,
                                            pf(pb + 15), pf(pb + 16),
                                            achan, pf(pb + 9), Yb);
    };

    // block 1: (I,X,Y) = (B0,B1,B2) -> out B2; block 2: (B2,B0,B1) -> out B1
    run_block(4, 1, sc1, false, B0, B1, B2);
    run_block(21, 4, sc2, true, B2, B0, B1);

    // final: relu(bn(pw(flip(B1), w_out))) -> d_out (f32)
    pw_mfma<128, 1, true, true, false, true, false, false><<<PW_GRID, blk, 0, stream>>>(
        B1, wbf + 7 * 16384, pf(3), OUT, nullptr, nullptr);
}